// Round 19
// baseline (192.076 us; speedup 1.0000x reference)
//
#include <hip/hip_runtime.h>

typedef __attribute__((ext_vector_type(8))) short short8;
typedef __attribute__((ext_vector_type(4))) float f32x4;

static __device__ __forceinline__ float bf2f(unsigned short u) {
    unsigned int x = ((unsigned int)u) << 16;
    union { unsigned int i; float f; } c; c.i = x; return c.f;
}
static __device__ __forceinline__ unsigned short f2bf(float f) {
    union { float f; unsigned int i; } c; c.f = f;
    unsigned int x = c.i;
    unsigned int r = (x + 0x7FFFu + ((x >> 16) & 1u)) >> 16;
    return (unsigned short)r;
}
static __device__ __forceinline__ void glds16(const char* g, char* l) {
    __builtin_amdgcn_global_load_lds(
        (const __attribute__((address_space(1))) unsigned int*)g,
        (__attribute__((address_space(3))) unsigned int*)l, 16, 0, 0);
}

// ---------------- prepack W2 scaled by rstd (norm folded from part1) + fold bias ----------------
// Blocks [0,nPre): reduce part1 -> stats in LDS, then prepack W2*rstd.
// Block nPre: reduce part1 for both batches, fold bias.
__global__ void prepack_scaled_fold(const float* __restrict__ W, const float2* __restrict__ part1,
                                    unsigned short* __restrict__ Wp, const float* __restrict__ b2,
                                    float* __restrict__ b2out, int S, int nPre, int N, int NBLK) {
    const int tid = threadIdx.x;
    if ((int)blockIdx.x < nPre) {
        const int b = (int)((blockIdx.x * 256) / (S * 512));
        __shared__ float2 stl[128];
        __shared__ float sh[2][2][128];
        {
            int c = tid & 127, r = tid >> 7;
            float s = 0.f, sq = 0.f;
            const float2* P = part1 + ((size_t)b * NBLK) * 128 + c;
            for (int i = r; i < NBLK; i += 2) {
                float2 v = P[(size_t)i * 128];
                s += v.x; sq += v.y;
            }
            sh[r][0][c] = s; sh[r][1][c] = sq;
            __syncthreads();
            if (r == 0) {
                s += sh[1][0][c]; sq += sh[1][1][c];
                float mu = s / N;
                stl[c] = make_float2(mu, rsqrtf(sq / N - mu * mu));
            }
            __syncthreads();
        }
        int gtid = blockIdx.x * 256 + tid;
        const int Cin = 128;
        int rem = gtid - b * S * 512;
        int lane = rem & 63;
        int f = (rem >> 6) & 7;
        int s = rem >> 9;
        int o = f * 16 + (lane & 15);
        int kbase = s * 32 + 8 * (lane >> 4);
        unsigned short* dst = Wp + (size_t)gtid * 8;
#pragma unroll
        for (int j = 0; j < 8; ++j) {
            int kk = kbase + j;
            int t = kk / Cin;
            int c = kk - t * Cin;
            dst[j] = f2bf(W[((size_t)o * Cin + c) * 7 + t] * stl[c].y);
        }
    } else {
        // fold: b2'[b][o] = b2[o] - sum_{c,t} W2[o][c][t]*rstd[b][c]*mu[b][c]
        int bb = tid >> 7, o = tid & 127;
        float s = 0.f, sq = 0.f;
        const float2* P = part1 + ((size_t)bb * NBLK) * 128 + o;  // o as channel here
        for (int i = 0; i < NBLK; ++i) {
            float2 v = P[(size_t)i * 128];
            s += v.x; sq += v.y;
        }
        float mu = s / N;
        float rstd = rsqrtf(sq / N - mu * mu);
        __shared__ float sm[2][128];
        sm[bb][o] = mu * rstd;
        __syncthreads();
        float sum = 0.f;
        for (int c = 0; c < 128; ++c) {
            float ws = 0.f;
#pragma unroll
            for (int t = 0; t < 7; ++t) ws += W[((size_t)o * 128 + c) * 7 + t];
            sum += ws * sm[bb][c];
        }
        b2out[bb * 128 + o] = b2[o] - sum;
    }
}

// ---------------- fused transpose v2 + static-W prepack ----------------
// y in [0,6): fp32 [B][C][N] -> bf16 [B][N][256], 64n x 64c tiles, single LDS
// buffer [64][65] fp32 (16.9KB, high occupancy). y == 6: prepack both static W.
__global__ void transpose_cast2(const float* __restrict__ up, const float* __restrict__ down,
                                unsigned short* __restrict__ upT, unsigned short* __restrict__ catT,
                                const float* __restrict__ W_up, const float* __restrict__ W_1,
                                unsigned short* __restrict__ Wp0, unsigned short* __restrict__ Wp1,
                                int S1, int N) {
    int y = blockIdx.y;
    if (y == 6) {
        if (blockIdx.z != 0) return;
        int units = 2 * S1 * 2;   // 2*S1*512 threads / 256
        for (int u = blockIdx.x; u < units; u += gridDim.x) {
            int tid = u * 256 + threadIdx.x;
            const float* W = (tid < S1 * 512) ? W_up : W_1;
            unsigned short* Wp = (tid < S1 * 512) ? Wp0 : Wp1;
            int rem = (tid < S1 * 512) ? tid : tid - S1 * 512;
            const int Cin = 256;
            int lane = rem & 63;
            int f = (rem >> 6) & 7;
            int s = rem >> 9;
            int o = f * 16 + (lane & 15);
            int kbase = s * 32 + 8 * (lane >> 4);
            unsigned short* dst = Wp + (size_t)rem * 8;
#pragma unroll
            for (int j = 0; j < 8; ++j) {
                int kk = kbase + j;
                int t = kk / Cin;
                int c = kk - t * Cin;
                dst[j] = f2bf(W[((size_t)o * Cin + c) * 7 + t]);
            }
        }
        return;
    }

    __shared__ float tile[64][65];
    int b = blockIdx.z;
    const float* in;  unsigned short* outp;  int c0, coff, C;
    if (y < 4) { in = up;   outp = upT;  c0 = y * 64;       coff = 0;   C = 256; }
    else       { in = down; outp = catT; c0 = (y - 4) * 64; coff = 128; C = 128; }
    int n0 = blockIdx.x * 64;
    const float* inb = in + (size_t)b * C * N;
    unsigned short* outb = outp + (size_t)b * N * 256;
    int tid = threadIdx.x;

    int nq = tid & 15, c_l = tid >> 4;
    bool nv = (n0 + nq * 4) < N;   // N%4==0 -> all-or-nothing per quad
#pragma unroll
    for (int ci = 0; ci < 4; ++ci) {
        int cl = ci * 16 + c_l;
        float4 v = make_float4(0.f, 0.f, 0.f, 0.f);
        if (nv) v = *reinterpret_cast<const float4*>(inb + (size_t)(c0 + cl) * N + n0 + nq * 4);
        tile[cl][nq * 4 + 0] = v.x;
        tile[cl][nq * 4 + 1] = v.y;
        tile[cl][nq * 4 + 2] = v.z;
        tile[cl][nq * 4 + 3] = v.w;
    }
    __syncthreads();
    int c8 = tid & 7, n_l0 = tid >> 3;
#pragma unroll
    for (int p = 0; p < 2; ++p) {
        int n_l = p * 32 + n_l0;
        int n = n0 + n_l;
        if (n < N) {
            short8 u;
#pragma unroll
            for (int j = 0; j < 8; ++j) u[j] = (short)f2bf(tile[c8 * 8 + j][n_l]);
            *reinterpret_cast<short8*>(&outb[(size_t)n * 256 + coff + c0 + c8 * 8]) = u;
        }
    }
}

// ---------------- GEMM-ified gather-conv: 256 pts x 128 couts, 8 waves (round-9 proven) ----------------
template<int CS, int LD, bool STATS>
__global__ __launch_bounds__(512, 2) void conv_gemm(
    const unsigned short* __restrict__ src,
    const int* __restrict__ nbrs,
    const unsigned short* __restrict__ Wp, size_t w_bstride_bytes,
    const float* __restrict__ bias, int bias_bstride,
    unsigned short* __restrict__ dst,
    float2* __restrict__ part,
    int N, int coff)
{
    constexpr int ROWB = CS * 2;
    constexpr int SPT  = CS / 32;   // k-steps per tap
    constexpr int S    = SPT * 7;   // total k-steps
    constexpr int BUFB = 24576;     // 16KB A + 8KB W per buffer

    const int tid  = threadIdx.x;
    const int lane = tid & 63;
    const int wid  = tid >> 6;      // 0..7
    const int pg   = wid & 3;       // point quarter (compute)
    const int h    = wid >> 2;      // cout half (compute)
    const int l15  = lane & 15;
    const int ks   = lane >> 4;
    const int b    = blockIdx.y;
    const int pblk = blockIdx.x * 256;

    const char* srcb = (const char*)src + (size_t)b * N * ROWB;
    const char* wbc  = (const char*)Wp + (size_t)b * w_bstride_bytes;

    __shared__ char smem[4 * BUFB];   // 96KB

    int roffA[14];
    {
        int p = pblk + wid * 32 + (lane & 31);
        int pe = p < N ? p : N - 1;
        int offs[7];
        offs[0] = pe * ROWB;
        const int* nb = nbrs + ((size_t)b * N + pe) * 6;
#pragma unroll
        for (int t = 1; t < 7; ++t) offs[t] = nb[t - 1] * ROWB;
#pragma unroll
        for (int t = 0; t < 7; ++t)
#pragma unroll
            for (int i = 0; i < 2; ++i)
                roffA[t * 2 + i] = __shfl(offs[t], i * 16 + (lane >> 2));
    }
    asm volatile("s_waitcnt vmcnt(0)" ::: "memory");
    __builtin_amdgcn_sched_barrier(0);

    const int asw = (((lane & 3) ^ ((lane >> 2) & 3) ^ ((lane >> 4) & 3)) << 4);

    auto stage_all = [&](int t, int kk, int s, int buf) {
        char* base = smem + buf * BUFB;
#pragma unroll
        for (int i = 0; i < 2; ++i)
            glds16(srcb + roffA[t * 2 + i] + kk * 64 + asw,
                   base + (wid * 2 + i) * 1024);
        glds16(wbc + (size_t)s * 8192 + wid * 1024 + lane * 16,
               base + 16384 + wid * 1024);
    };

    f32x4 acc[4][4];
#pragma unroll
    for (int rg = 0; rg < 4; ++rg)
#pragma unroll
        for (int fi = 0; fi < 4; ++fi) acc[rg][fi] = (f32x4){0.f, 0.f, 0.f, 0.f};

    stage_all(0, 0, 0, 0);
    stage_all(1 / SPT, 1 % SPT, 1, 1);
    stage_all(2 / SPT, 2 % SPT, 2, 2);

    const int arsw = (((l15 & 3) ^ ((l15 >> 2) & 3)) << 4);

#pragma unroll
    for (int t = 0; t < 7; ++t) {
#pragma unroll
        for (int kk = 0; kk < SPT; ++kk) {
            const int s = t * SPT + kk;
            if (s + 2 < S)      { asm volatile("s_waitcnt vmcnt(6)" ::: "memory"); }
            else if (s + 1 < S) { asm volatile("s_waitcnt vmcnt(3)" ::: "memory"); }
            else                { asm volatile("s_waitcnt vmcnt(0)" ::: "memory"); }
            __builtin_amdgcn_sched_barrier(0);
            __builtin_amdgcn_s_barrier();
            __builtin_amdgcn_sched_barrier(0);
            if (s + 3 < S) {
                const int s3 = s + 3;
                stage_all(s3 / SPT, s3 % SPT, s3, s3 & 3);
            }

            const char* Ab = smem + (s & 3) * BUFB;
            const char* Wb = Ab + 16384;
            short8 a[4], w[4];
#pragma unroll
            for (int rg = 0; rg < 4; ++rg)
                a[rg] = *(const short8*)(Ab + (pg * 64 + rg * 16 + l15) * 64 +
                                         ((ks << 4) ^ arsw));
#pragma unroll
            for (int fi = 0; fi < 4; ++fi)
                w[fi] = *(const short8*)(Wb + (h * 4 + fi) * 1024 + lane * 16);
            __builtin_amdgcn_s_setprio(1);
#pragma unroll
            for (int rg = 0; rg < 4; ++rg)
#pragma unroll
                for (int fi = 0; fi < 4; ++fi)
                    acc[rg][fi] = __builtin_amdgcn_mfma_f32_16x16x32_bf16(
                        a[rg], w[fi], acc[rg][fi], 0, 0, 0);
            __builtin_amdgcn_s_setprio(0);
        }
    }

    const float* biasb = bias + (size_t)b * bias_bstride + h * 64;
    float bias_v[4];
#pragma unroll
    for (int fi = 0; fi < 4; ++fi) bias_v[fi] = biasb[fi * 16 + l15];

    unsigned short* dstb = dst + (size_t)b * N * LD + coff + h * 64;
#pragma unroll
    for (int rg = 0; rg < 4; ++rg) {
#pragma unroll
        for (int r = 0; r < 4; ++r) {
            int p = pblk + pg * 64 + rg * 16 + ks * 4 + r;
            if (p < N) {
#pragma unroll
                for (int fi = 0; fi < 4; ++fi)
                    dstb[(size_t)p * LD + fi * 16 + l15] = f2bf(acc[rg][fi][r] + bias_v[fi]);
            }
        }
    }

    if constexpr (STATS) {
        float s4[4], q4[4];
#pragma unroll
        for (int fi = 0; fi < 4; ++fi) { s4[fi] = 0.f; q4[fi] = 0.f; }
#pragma unroll
        for (int rg = 0; rg < 4; ++rg) {
#pragma unroll
            for (int r = 0; r < 4; ++r) {
                int p = pblk + pg * 64 + rg * 16 + ks * 4 + r;
                if (p < N) {
#pragma unroll
                    for (int fi = 0; fi < 4; ++fi) {
                        float v = acc[rg][fi][r] + bias_v[fi];
                        s4[fi] += v; q4[fi] += v * v;
                    }
                }
            }
        }
#pragma unroll
        for (int fi = 0; fi < 4; ++fi) {
            s4[fi] += __shfl_xor(s4[fi], 16); s4[fi] += __shfl_xor(s4[fi], 32);
            q4[fi] += __shfl_xor(q4[fi], 16); q4[fi] += __shfl_xor(q4[fi], 32);
        }
        __syncthreads();
        float* shs = (float*)smem;       // [8][64]
        float* shq = shs + 512;
        if (lane < 16) {
#pragma unroll
            for (int fi = 0; fi < 4; ++fi) {
                shs[wid * 64 + fi * 16 + l15] = s4[fi];
                shq[wid * 64 + fi * 16 + l15] = q4[fi];
            }
        }
        __syncthreads();
        if (tid < 128) {
            int c = tid;
            int hh = c >> 6, cl = c & 63;
            float ss = 0.f, qq = 0.f;
#pragma unroll
            for (int p4 = 0; p4 < 4; ++p4) {
                ss += shs[(hh * 4 + p4) * 64 + cl];
                qq += shq[(hh * 4 + p4) * 64 + cl];
            }
            part[((size_t)b * gridDim.x + blockIdx.x) * 128 + c] = make_float2(ss, qq);
        }
    }
}

// ---------------- final v3: fused stats reduce + normalize + residual + transpose ----------------
// Block: 32 o x 512 n (4 sub-tiles of 128). Preamble reduces part1/part2 for its 32
// channels (L2-resident). out[b][o][n] = (z-mu2)*rstd2 + (x1-mu1)*rstd1, float4 stores.
__global__ void final_k(const unsigned short* __restrict__ z, const unsigned short* __restrict__ x1,
                        const float2* __restrict__ part1, const float2* __restrict__ part2,
                        float* __restrict__ out, int N, int NBLK) {
    __shared__ float tile[32][133];
    __shared__ float2 stl[2][32];
    int b = blockIdx.z;
    int n0 = blockIdx.x * 512, o0 = blockIdx.y * 32;
    int tid = threadIdx.x;  // 256

    {   // stats reduce: 4 threads per (st, ch), serial over NBLK/4
        int w = tid >> 2, rr = tid & 3;
        int st = w >> 5, ch = w & 31;
        const float2* P = (st ? part2 : part1) + ((size_t)b * NBLK) * 128 + o0 + ch;
        float s = 0.f, sq = 0.f;
        for (int i = rr; i < NBLK; i += 4) {
            float2 v = P[(size_t)i * 128];
            s += v.x; sq += v.y;
        }
        s += __shfl_xor(s, 1); sq += __shfl_xor(sq, 1);
        s += __shfl_xor(s, 2); sq += __shfl_xor(sq, 2);
        if (rr == 0) {
            float mu = s / N;
            stl[st][ch] = make_float2(mu, rsqrtf(sq / N - mu * mu));
        }
    }
    __syncthreads();

    const unsigned short* zb = z  + (size_t)b * N * 128;
    const unsigned short* xb = x1 + (size_t)b * N * 128;
    int oq = tid & 3, n_l0 = tid >> 2;
    float m1[8], r1[8], m2[8], r2[8];
#pragma unroll
    for (int j = 0; j < 8; ++j) {
        float2 s1 = stl[0][oq * 8 + j];
        float2 s2 = stl[1][oq * 8 + j];
        m1[j] = s1.x; r1[j] = s1.y; m2[j] = s2.x; r2[j] = s2.y;
    }
    float* ob = out + (size_t)b * 128 * N;
    int nq = tid & 31, o_l = tid >> 5;

    for (int sub = 0; sub < 4; ++sub) {
        int n0s = n0 + sub * 128;
        if (n0s >= N) break;   // block-uniform
#pragma unroll
        for (int p = 0; p < 2; ++p) {
            int n_l = p * 64 + n_l0;
            int n = n0s + n_l;
            if (n < N) {
                short8 zv = *reinterpret_cast<const short8*>(zb + (size_t)n * 128 + o0 + oq * 8);
                short8 xv = *reinterpret_cast<const short8*>(xb + (size_t)n * 128 + o0 + oq * 8);
#pragma unroll
                for (int j = 0; j < 8; ++j) {
                    float v = (bf2f((unsigned short)zv[j]) - m2[j]) * r2[j] +
                              (bf2f((unsigned short)xv[j]) - m1[j]) * r1[j];
                    tile[oq * 8 + j][n_l] = v;
                }
            }
        }
        __syncthreads();
        int n = n0s + nq * 4;
        if (n < N) {
#pragma unroll
            for (int pi = 0; pi < 4; ++pi) {
                int orow = pi * 8 + o_l;
                float4 v;
                v.x = tile[orow][nq * 4 + 0];
                v.y = tile[orow][nq * 4 + 1];
                v.z = tile[orow][nq * 4 + 2];
                v.w = tile[orow][nq * 4 + 3];
                *reinterpret_cast<float4*>(&ob[(size_t)(o0 + orow) * N + n]) = v;
            }
        }
        __syncthreads();
    }
}

extern "C" void kernel_launch(void* const* d_in, const int* in_sizes, int n_in,
                              void* d_out, int out_size, void* d_ws, size_t ws_size,
                              hipStream_t stream) {
    const float* from_up   = (const float*)d_in[0];  // [2,256,30000]
    const float* from_down = (const float*)d_in[1];  // [2,128,30000]
    const int*   neighbors = (const int*)d_in[2];    // [2,30000,6]
    const float* W_up = (const float*)d_in[3];
    const float* b_up = (const float*)d_in[4];
    const float* W_1  = (const float*)d_in[5];
    const float* b_1  = (const float*)d_in[6];
    const float* W_2  = (const float*)d_in[7];
    const float* b_2  = (const float*)d_in[8];
    float* out = (float*)d_out;

    const int B = 2, N = 30000;
    const int S1 = 56, S3 = 28;        // K-steps: 1792/32, 896/32
    const int NBLK = (N + 255) / 256;  // 118 conv blocks per batch

    char* ws = (char*)d_ws;
    size_t off = 0;
    auto alloc = [&](size_t bytes) {
        char* p = ws + off;
        off += (bytes + 255) & ~(size_t)255;
        return p;
    };
    unsigned short* upT   = (unsigned short*)alloc((size_t)B * N * 256 * 2);
    unsigned short* catT  = (unsigned short*)alloc((size_t)B * N * 256 * 2);
    unsigned short* x1    = (unsigned short*)alloc((size_t)B * N * 128 * 2);
    unsigned short* Wp0   = (unsigned short*)alloc((size_t)S1 * 512 * 8 * 2);
    unsigned short* Wp1   = (unsigned short*)alloc((size_t)S1 * 512 * 8 * 2);
    unsigned short* Wp2b  = (unsigned short*)alloc((size_t)B * S3 * 512 * 8 * 2);
    float*  b2fold = (float*)alloc((size_t)B * 128 * 4);
    float2* part1  = (float2*)alloc((size_t)B * NBLK * 128 * 8);
    float2* part2  = (float2*)alloc((size_t)B * NBLK * 128 * 8);
    unsigned short* zbuf = upT;  // reuse (upT dead after conv1)

    // transpose both inputs + prepack both static weights (one launch)
    transpose_cast2<<<dim3((N + 63) / 64, 7, B), 256, 0, stream>>>(
        from_up, from_down, upT, catT, W_up, W_1, Wp0, Wp1, S1, N);

    dim3 cgrid(NBLK, B);
    // conv1: upT (Cin=256) -> catT[:, 0:128]
    conv_gemm<256, 256, false><<<cgrid, 512, 0, stream>>>(
        upT, neighbors, Wp0, 0, b_up, 0, catT, nullptr, N, 0);
    // conv2: catT (Cin=256) -> x1, stats partials -> part1
    conv_gemm<256, 128, true><<<cgrid, 512, 0, stream>>>(
        catT, neighbors, Wp1, 0, b_1, 0, x1, part1, N, 0);

    // fold norm1 into conv3's weights/bias (reduces part1 internally)
    int nPre = (B * S3 * 512) / 256;  // 112
    prepack_scaled_fold<<<nPre + 1, 256, 0, stream>>>(
        W_2, (const float2*)part1, Wp2b, b_2, b2fold, S3, nPre, N, NBLK);

    // conv3: x1 (Cin=128, scaled weights) -> zbuf, stats partials -> part2
    conv_gemm<128, 128, true><<<cgrid, 512, 0, stream>>>(
        x1, neighbors, Wp2b, (size_t)S3 * 8192, b2fold, 128, zbuf, part2, N, 0);

    // final: reduce part1/part2, normalize z, add recomputed x1n, transpose out
    final_k<<<dim3((N + 511) / 512, 4, B), 256, 0, stream>>>(
        zbuf, x1, (const float2*)part1, (const float2*)part2, out, N, NBLK);
}

// Round 20
// 184.351 us; speedup vs baseline: 1.0419x; 1.0419x over previous
//
#include <hip/hip_runtime.h>

typedef __attribute__((ext_vector_type(8))) short short8;
typedef __attribute__((ext_vector_type(4))) float f32x4;

static __device__ __forceinline__ float bf2f(unsigned short u) {
    unsigned int x = ((unsigned int)u) << 16;
    union { unsigned int i; float f; } c; c.i = x; return c.f;
}
static __device__ __forceinline__ unsigned short f2bf(float f) {
    union { float f; unsigned int i; } c; c.f = f;
    unsigned int x = c.i;
    unsigned int r = (x + 0x7FFFu + ((x >> 16) & 1u)) >> 16;
    return (unsigned short)r;
}
static __device__ __forceinline__ void glds16(const char* g, char* l) {
    __builtin_amdgcn_global_load_lds(
        (const __attribute__((address_space(1))) unsigned int*)g,
        (__attribute__((address_space(3))) unsigned int*)l, 16, 0, 0);
}

// ---------------- prepack W2 scaled by rstd (norm folded from part1) + fold bias ----------------
// Blocks [0,nPre): reduce part1 -> stats in LDS (unrolled, ILP), then prepack W2*rstd.
// Block nPre: reduce part1 for both batches, fold bias.
__global__ void prepack_scaled_fold(const float* __restrict__ W, const float2* __restrict__ part1,
                                    unsigned short* __restrict__ Wp, const float* __restrict__ b2,
                                    float* __restrict__ b2out, int S, int nPre, int N, int NBLK) {
    const int tid = threadIdx.x;
    if ((int)blockIdx.x < nPre) {
        const int b = (int)((blockIdx.x * 256) / (S * 512));
        __shared__ float2 stl[128];
        __shared__ float sh[2][2][128];
        {
            int c = tid & 127, r = tid >> 7;
            float s = 0.f, sq = 0.f;
            const float2* P = part1 + ((size_t)b * NBLK) * 128 + c;
#pragma unroll 4
            for (int i = r; i < NBLK; i += 2) {
                float2 v = P[(size_t)i * 128];
                s += v.x; sq += v.y;
            }
            sh[r][0][c] = s; sh[r][1][c] = sq;
            __syncthreads();
            if (r == 0) {
                s += sh[1][0][c]; sq += sh[1][1][c];
                float mu = s / N;
                stl[c] = make_float2(mu, rsqrtf(sq / N - mu * mu));
            }
            __syncthreads();
        }
        int gtid = blockIdx.x * 256 + tid;
        const int Cin = 128;
        int rem = gtid - b * S * 512;
        int lane = rem & 63;
        int f = (rem >> 6) & 7;
        int s = rem >> 9;
        int o = f * 16 + (lane & 15);
        int kbase = s * 32 + 8 * (lane >> 4);
        unsigned short* dst = Wp + (size_t)gtid * 8;
#pragma unroll
        for (int j = 0; j < 8; ++j) {
            int kk = kbase + j;
            int t = kk / Cin;
            int c = kk - t * Cin;
            dst[j] = f2bf(W[((size_t)o * Cin + c) * 7 + t] * stl[c].y);
        }
    } else {
        // fold: b2'[b][o] = b2[o] - sum_{c,t} W2[o][c][t]*rstd[b][c]*mu[b][c]
        int bb = tid >> 7, o = tid & 127;
        float s = 0.f, sq = 0.f;
        const float2* P = part1 + ((size_t)bb * NBLK) * 128 + o;  // o as channel here
#pragma unroll 4
        for (int i = 0; i < NBLK; ++i) {
            float2 v = P[(size_t)i * 128];
            s += v.x; sq += v.y;
        }
        float mu = s / N;
        float rstd = rsqrtf(sq / N - mu * mu);
        __shared__ float sm[2][128];
        sm[bb][o] = mu * rstd;
        __syncthreads();
        float sum = 0.f;
#pragma unroll 2
        for (int c = 0; c < 128; ++c) {
            float ws = 0.f;
#pragma unroll
            for (int t = 0; t < 7; ++t) ws += W[((size_t)o * 128 + c) * 7 + t];
            sum += ws * sm[bb][c];
        }
        b2out[bb * 128 + o] = b2[o] - sum;
    }
}

// ---------------- fused transpose v2 + static-W prepack ----------------
// y in [0,6): fp32 [B][C][N] -> bf16 [B][N][256], 64n x 64c tiles, single LDS
// buffer [64][65] fp32 (16.9KB, high occupancy). y == 6: prepack both static W.
__global__ void transpose_cast2(const float* __restrict__ up, const float* __restrict__ down,
                                unsigned short* __restrict__ upT, unsigned short* __restrict__ catT,
                                const float* __restrict__ W_up, const float* __restrict__ W_1,
                                unsigned short* __restrict__ Wp0, unsigned short* __restrict__ Wp1,
                                int S1, int N) {
    int y = blockIdx.y;
    if (y == 6) {
        if (blockIdx.z != 0) return;
        int units = 2 * S1 * 2;   // 2*S1*512 threads / 256
        for (int u = blockIdx.x; u < units; u += gridDim.x) {
            int tid = u * 256 + threadIdx.x;
            const float* W = (tid < S1 * 512) ? W_up : W_1;
            unsigned short* Wp = (tid < S1 * 512) ? Wp0 : Wp1;
            int rem = (tid < S1 * 512) ? tid : tid - S1 * 512;
            const int Cin = 256;
            int lane = rem & 63;
            int f = (rem >> 6) & 7;
            int s = rem >> 9;
            int o = f * 16 + (lane & 15);
            int kbase = s * 32 + 8 * (lane >> 4);
            unsigned short* dst = Wp + (size_t)rem * 8;
#pragma unroll
            for (int j = 0; j < 8; ++j) {
                int kk = kbase + j;
                int t = kk / Cin;
                int c = kk - t * Cin;
                dst[j] = f2bf(W[((size_t)o * Cin + c) * 7 + t]);
            }
        }
        return;
    }

    __shared__ float tile[64][65];
    int b = blockIdx.z;
    const float* in;  unsigned short* outp;  int c0, coff, C;
    if (y < 4) { in = up;   outp = upT;  c0 = y * 64;       coff = 0;   C = 256; }
    else       { in = down; outp = catT; c0 = (y - 4) * 64; coff = 128; C = 128; }
    int n0 = blockIdx.x * 64;
    const float* inb = in + (size_t)b * C * N;
    unsigned short* outb = outp + (size_t)b * N * 256;
    int tid = threadIdx.x;

    int nq = tid & 15, c_l = tid >> 4;
    bool nv = (n0 + nq * 4) < N;   // N%4==0 -> all-or-nothing per quad
#pragma unroll
    for (int ci = 0; ci < 4; ++ci) {
        int cl = ci * 16 + c_l;
        float4 v = make_float4(0.f, 0.f, 0.f, 0.f);
        if (nv) v = *reinterpret_cast<const float4*>(inb + (size_t)(c0 + cl) * N + n0 + nq * 4);
        tile[cl][nq * 4 + 0] = v.x;
        tile[cl][nq * 4 + 1] = v.y;
        tile[cl][nq * 4 + 2] = v.z;
        tile[cl][nq * 4 + 3] = v.w;
    }
    __syncthreads();
    int c8 = tid & 7, n_l0 = tid >> 3;
#pragma unroll
    for (int p = 0; p < 2; ++p) {
        int n_l = p * 32 + n_l0;
        int n = n0 + n_l;
        if (n < N) {
            short8 u;
#pragma unroll
            for (int j = 0; j < 8; ++j) u[j] = (short)f2bf(tile[c8 * 8 + j][n_l]);
            *reinterpret_cast<short8*>(&outb[(size_t)n * 256 + coff + c0 + c8 * 8]) = u;
        }
    }
}

// ---------------- GEMM-ified gather-conv: 256 pts x 128 couts, 8 waves (round-9 proven) ----------------
template<int CS, int LD, bool STATS>
__global__ __launch_bounds__(512, 2) void conv_gemm(
    const unsigned short* __restrict__ src,
    const int* __restrict__ nbrs,
    const unsigned short* __restrict__ Wp, size_t w_bstride_bytes,
    const float* __restrict__ bias, int bias_bstride,
    unsigned short* __restrict__ dst,
    float2* __restrict__ part,
    int N, int coff)
{
    constexpr int ROWB = CS * 2;
    constexpr int SPT  = CS / 32;   // k-steps per tap
    constexpr int S    = SPT * 7;   // total k-steps
    constexpr int BUFB = 24576;     // 16KB A + 8KB W per buffer

    const int tid  = threadIdx.x;
    const int lane = tid & 63;
    const int wid  = tid >> 6;      // 0..7
    const int pg   = wid & 3;       // point quarter (compute)
    const int h    = wid >> 2;      // cout half (compute)
    const int l15  = lane & 15;
    const int ks   = lane >> 4;
    const int b    = blockIdx.y;
    const int pblk = blockIdx.x * 256;

    const char* srcb = (const char*)src + (size_t)b * N * ROWB;
    const char* wbc  = (const char*)Wp + (size_t)b * w_bstride_bytes;

    __shared__ char smem[4 * BUFB];   // 96KB

    int roffA[14];
    {
        int p = pblk + wid * 32 + (lane & 31);
        int pe = p < N ? p : N - 1;
        int offs[7];
        offs[0] = pe * ROWB;
        const int* nb = nbrs + ((size_t)b * N + pe) * 6;
#pragma unroll
        for (int t = 1; t < 7; ++t) offs[t] = nb[t - 1] * ROWB;
#pragma unroll
        for (int t = 0; t < 7; ++t)
#pragma unroll
            for (int i = 0; i < 2; ++i)
                roffA[t * 2 + i] = __shfl(offs[t], i * 16 + (lane >> 2));
    }
    asm volatile("s_waitcnt vmcnt(0)" ::: "memory");
    __builtin_amdgcn_sched_barrier(0);

    const int asw = (((lane & 3) ^ ((lane >> 2) & 3) ^ ((lane >> 4) & 3)) << 4);

    auto stage_all = [&](int t, int kk, int s, int buf) {
        char* base = smem + buf * BUFB;
#pragma unroll
        for (int i = 0; i < 2; ++i)
            glds16(srcb + roffA[t * 2 + i] + kk * 64 + asw,
                   base + (wid * 2 + i) * 1024);
        glds16(wbc + (size_t)s * 8192 + wid * 1024 + lane * 16,
               base + 16384 + wid * 1024);
    };

    f32x4 acc[4][4];
#pragma unroll
    for (int rg = 0; rg < 4; ++rg)
#pragma unroll
        for (int fi = 0; fi < 4; ++fi) acc[rg][fi] = (f32x4){0.f, 0.f, 0.f, 0.f};

    stage_all(0, 0, 0, 0);
    stage_all(1 / SPT, 1 % SPT, 1, 1);
    stage_all(2 / SPT, 2 % SPT, 2, 2);

    const int arsw = (((l15 & 3) ^ ((l15 >> 2) & 3)) << 4);

#pragma unroll
    for (int t = 0; t < 7; ++t) {
#pragma unroll
        for (int kk = 0; kk < SPT; ++kk) {
            const int s = t * SPT + kk;
            if (s + 2 < S)      { asm volatile("s_waitcnt vmcnt(6)" ::: "memory"); }
            else if (s + 1 < S) { asm volatile("s_waitcnt vmcnt(3)" ::: "memory"); }
            else                { asm volatile("s_waitcnt vmcnt(0)" ::: "memory"); }
            __builtin_amdgcn_sched_barrier(0);
            __builtin_amdgcn_s_barrier();
            __builtin_amdgcn_sched_barrier(0);
            if (s + 3 < S) {
                const int s3 = s + 3;
                stage_all(s3 / SPT, s3 % SPT, s3, s3 & 3);
            }

            const char* Ab = smem + (s & 3) * BUFB;
            const char* Wb = Ab + 16384;
            short8 a[4], w[4];
#pragma unroll
            for (int rg = 0; rg < 4; ++rg)
                a[rg] = *(const short8*)(Ab + (pg * 64 + rg * 16 + l15) * 64 +
                                         ((ks << 4) ^ arsw));
#pragma unroll
            for (int fi = 0; fi < 4; ++fi)
                w[fi] = *(const short8*)(Wb + (h * 4 + fi) * 1024 + lane * 16);
            __builtin_amdgcn_s_setprio(1);
#pragma unroll
            for (int rg = 0; rg < 4; ++rg)
#pragma unroll
                for (int fi = 0; fi < 4; ++fi)
                    acc[rg][fi] = __builtin_amdgcn_mfma_f32_16x16x32_bf16(
                        a[rg], w[fi], acc[rg][fi], 0, 0, 0);
            __builtin_amdgcn_s_setprio(0);
        }
    }

    const float* biasb = bias + (size_t)b * bias_bstride + h * 64;
    float bias_v[4];
#pragma unroll
    for (int fi = 0; fi < 4; ++fi) bias_v[fi] = biasb[fi * 16 + l15];

    unsigned short* dstb = dst + (size_t)b * N * LD + coff + h * 64;
#pragma unroll
    for (int rg = 0; rg < 4; ++rg) {
#pragma unroll
        for (int r = 0; r < 4; ++r) {
            int p = pblk + pg * 64 + rg * 16 + ks * 4 + r;
            if (p < N) {
#pragma unroll
                for (int fi = 0; fi < 4; ++fi)
                    dstb[(size_t)p * LD + fi * 16 + l15] = f2bf(acc[rg][fi][r] + bias_v[fi]);
            }
        }
    }

    if constexpr (STATS) {
        float s4[4], q4[4];
#pragma unroll
        for (int fi = 0; fi < 4; ++fi) { s4[fi] = 0.f; q4[fi] = 0.f; }
#pragma unroll
        for (int rg = 0; rg < 4; ++rg) {
#pragma unroll
            for (int r = 0; r < 4; ++r) {
                int p = pblk + pg * 64 + rg * 16 + ks * 4 + r;
                if (p < N) {
#pragma unroll
                    for (int fi = 0; fi < 4; ++fi) {
                        float v = acc[rg][fi][r] + bias_v[fi];
                        s4[fi] += v; q4[fi] += v * v;
                    }
                }
            }
        }
#pragma unroll
        for (int fi = 0; fi < 4; ++fi) {
            s4[fi] += __shfl_xor(s4[fi], 16); s4[fi] += __shfl_xor(s4[fi], 32);
            q4[fi] += __shfl_xor(q4[fi], 16); q4[fi] += __shfl_xor(q4[fi], 32);
        }
        __syncthreads();
        float* shs = (float*)smem;       // [8][64]
        float* shq = shs + 512;
        if (lane < 16) {
#pragma unroll
            for (int fi = 0; fi < 4; ++fi) {
                shs[wid * 64 + fi * 16 + l15] = s4[fi];
                shq[wid * 64 + fi * 16 + l15] = q4[fi];
            }
        }
        __syncthreads();
        if (tid < 128) {
            int c = tid;
            int hh = c >> 6, cl = c & 63;
            float ss = 0.f, qq = 0.f;
#pragma unroll
            for (int p4 = 0; p4 < 4; ++p4) {
                ss += shs[(hh * 4 + p4) * 64 + cl];
                qq += shq[(hh * 4 + p4) * 64 + cl];
            }
            part[((size_t)b * gridDim.x + blockIdx.x) * 128 + c] = make_float2(ss, qq);
        }
    }
}

// ---------------- final v3: fused stats reduce + normalize + residual + transpose ----------------
// Block: 32 o x 512 n (4 sub-tiles of 128). Preamble reduces part1/part2 for its 32
// channels (unrolled, L2-resident). out = (z-mu2)*rstd2 + (x1-mu1)*rstd1, float4 stores.
__global__ void final_k(const unsigned short* __restrict__ z, const unsigned short* __restrict__ x1,
                        const float2* __restrict__ part1, const float2* __restrict__ part2,
                        float* __restrict__ out, int N, int NBLK) {
    __shared__ float tile[32][133];
    __shared__ float2 stl[2][32];
    int b = blockIdx.z;
    int n0 = blockIdx.x * 512, o0 = blockIdx.y * 32;
    int tid = threadIdx.x;  // 256

    {   // stats reduce: 4 threads per (st, ch), unrolled for ILP
        int w = tid >> 2, rr = tid & 3;
        int st = w >> 5, ch = w & 31;
        const float2* P = (st ? part2 : part1) + ((size_t)b * NBLK) * 128 + o0 + ch;
        float s = 0.f, sq = 0.f;
#pragma unroll 4
        for (int i = rr; i < NBLK; i += 4) {
            float2 v = P[(size_t)i * 128];
            s += v.x; sq += v.y;
        }
        s += __shfl_xor(s, 1); sq += __shfl_xor(sq, 1);
        s += __shfl_xor(s, 2); sq += __shfl_xor(sq, 2);
        if (rr == 0) {
            float mu = s / N;
            stl[st][ch] = make_float2(mu, rsqrtf(sq / N - mu * mu));
        }
    }
    __syncthreads();

    const unsigned short* zb = z  + (size_t)b * N * 128;
    const unsigned short* xb = x1 + (size_t)b * N * 128;
    int oq = tid & 3, n_l0 = tid >> 2;
    float m1[8], r1[8], m2[8], r2[8];
#pragma unroll
    for (int j = 0; j < 8; ++j) {
        float2 s1 = stl[0][oq * 8 + j];
        float2 s2 = stl[1][oq * 8 + j];
        m1[j] = s1.x; r1[j] = s1.y; m2[j] = s2.x; r2[j] = s2.y;
    }
    float* ob = out + (size_t)b * 128 * N;
    int nq = tid & 31, o_l = tid >> 5;

    for (int sub = 0; sub < 4; ++sub) {
        int n0s = n0 + sub * 128;
        if (n0s >= N) break;   // block-uniform
#pragma unroll
        for (int p = 0; p < 2; ++p) {
            int n_l = p * 64 + n_l0;
            int n = n0s + n_l;
            if (n < N) {
                short8 zv = *reinterpret_cast<const short8*>(zb + (size_t)n * 128 + o0 + oq * 8);
                short8 xv = *reinterpret_cast<const short8*>(xb + (size_t)n * 128 + o0 + oq * 8);
#pragma unroll
                for (int j = 0; j < 8; ++j) {
                    float v = (bf2f((unsigned short)zv[j]) - m2[j]) * r2[j] +
                              (bf2f((unsigned short)xv[j]) - m1[j]) * r1[j];
                    tile[oq * 8 + j][n_l] = v;
                }
            }
        }
        __syncthreads();
        int n = n0s + nq * 4;
        if (n < N) {
#pragma unroll
            for (int pi = 0; pi < 4; ++pi) {
                int orow = pi * 8 + o_l;
                float4 v;
                v.x = tile[orow][nq * 4 + 0];
                v.y = tile[orow][nq * 4 + 1];
                v.z = tile[orow][nq * 4 + 2];
                v.w = tile[orow][nq * 4 + 3];
                *reinterpret_cast<float4*>(&ob[(size_t)(o0 + orow) * N + n]) = v;
            }
        }
        __syncthreads();
    }
}

extern "C" void kernel_launch(void* const* d_in, const int* in_sizes, int n_in,
                              void* d_out, int out_size, void* d_ws, size_t ws_size,
                              hipStream_t stream) {
    const float* from_up   = (const float*)d_in[0];  // [2,256,30000]
    const float* from_down = (const float*)d_in[1];  // [2,128,30000]
    const int*   neighbors = (const int*)d_in[2];    // [2,30000,6]
    const float* W_up = (const float*)d_in[3];
    const float* b_up = (const float*)d_in[4];
    const float* W_1  = (const float*)d_in[5];
    const float* b_1  = (const float*)d_in[6];
    const float* W_2  = (const float*)d_in[7];
    const float* b_2  = (const float*)d_in[8];
    float* out = (float*)d_out;

    const int B = 2, N = 30000;
    const int S1 = 56, S3 = 28;        // K-steps: 1792/32, 896/32
    const int NBLK = (N + 255) / 256;  // 118 conv blocks per batch

    char* ws = (char*)d_ws;
    size_t off = 0;
    auto alloc = [&](size_t bytes) {
        char* p = ws + off;
        off += (bytes + 255) & ~(size_t)255;
        return p;
    };
    unsigned short* upT   = (unsigned short*)alloc((size_t)B * N * 256 * 2);
    unsigned short* catT  = (unsigned short*)alloc((size_t)B * N * 256 * 2);
    unsigned short* x1    = (unsigned short*)alloc((size_t)B * N * 128 * 2);
    unsigned short* Wp0   = (unsigned short*)alloc((size_t)S1 * 512 * 8 * 2);
    unsigned short* Wp1   = (unsigned short*)alloc((size_t)S1 * 512 * 8 * 2);
    unsigned short* Wp2b  = (unsigned short*)alloc((size_t)B * S3 * 512 * 8 * 2);
    float*  b2fold = (float*)alloc((size_t)B * 128 * 4);
    float2* part1  = (float2*)alloc((size_t)B * NBLK * 128 * 8);
    float2* part2  = (float2*)alloc((size_t)B * NBLK * 128 * 8);
    unsigned short* zbuf = upT;  // reuse (upT dead after conv1)

    // transpose both inputs + prepack both static weights (one launch)
    transpose_cast2<<<dim3((N + 63) / 64, 7, B), 256, 0, stream>>>(
        from_up, from_down, upT, catT, W_up, W_1, Wp0, Wp1, S1, N);

    dim3 cgrid(NBLK, B);
    // conv1: upT (Cin=256) -> catT[:, 0:128]
    conv_gemm<256, 256, false><<<cgrid, 512, 0, stream>>>(
        upT, neighbors, Wp0, 0, b_up, 0, catT, nullptr, N, 0);
    // conv2: catT (Cin=256) -> x1, stats partials -> part1
    conv_gemm<256, 128, true><<<cgrid, 512, 0, stream>>>(
        catT, neighbors, Wp1, 0, b_1, 0, x1, part1, N, 0);

    // fold norm1 into conv3's weights/bias (reduces part1 internally)
    int nPre = (B * S3 * 512) / 256;  // 112
    prepack_scaled_fold<<<nPre + 1, 256, 0, stream>>>(
        W_2, (const float2*)part1, Wp2b, b_2, b2fold, S3, nPre, N, NBLK);

    // conv3: x1 (Cin=128, scaled weights) -> zbuf, stats partials -> part2
    conv_gemm<128, 128, true><<<cgrid, 512, 0, stream>>>(
        x1, neighbors, Wp2b, (size_t)S3 * 8192, b2fold, 128, zbuf, part2, N, 0);

    // final: reduce part1/part2, normalize z, add recomputed x1n, transpose out
    final_k<<<dim3((N + 511) / 512, 4, B), 256, 0, stream>>>(
        zbuf, x1, (const float2*)part1, (const float2*)part2, out, N, NBLK);
}

// Round 21
// 176.421 us; speedup vs baseline: 1.0887x; 1.0450x over previous
//
#include <hip/hip_runtime.h>

typedef __attribute__((ext_vector_type(8))) short short8;
typedef __attribute__((ext_vector_type(4))) float f32x4;

static __device__ __forceinline__ float bf2f(unsigned short u) {
    unsigned int x = ((unsigned int)u) << 16;
    union { unsigned int i; float f; } c; c.i = x; return c.f;
}
static __device__ __forceinline__ unsigned short f2bf(float f) {
    union { float f; unsigned int i; } c; c.f = f;
    unsigned int x = c.i;
    unsigned int r = (x + 0x7FFFu + ((x >> 16) & 1u)) >> 16;
    return (unsigned short)r;
}
static __device__ __forceinline__ void glds16(const char* g, char* l) {
    __builtin_amdgcn_global_load_lds(
        (const __attribute__((address_space(1))) unsigned int*)g,
        (__attribute__((address_space(3))) unsigned int*)l, 16, 0, 0);
}

// ---------------- prepack W2 scaled by rstd (norm folded) + fold bias, one kernel ----------------
__global__ void prepack_scaled_fold(const float* __restrict__ W, const float2* __restrict__ stats,
                                    unsigned short* __restrict__ Wp, const float* __restrict__ b2,
                                    float* __restrict__ b2out, int S, int nPre) {
    if ((int)blockIdx.x < nPre) {
        int tid = blockIdx.x * 256 + threadIdx.x;
        const int Cin = 128;
        int b = tid / (S * 512);
        int rem = tid - b * S * 512;
        int lane = rem & 63;
        int f = (rem >> 6) & 7;
        int s = rem >> 9;
        int o = f * 16 + (lane & 15);
        int kbase = s * 32 + 8 * (lane >> 4);
        unsigned short* dst = Wp + (size_t)tid * 8;
#pragma unroll
        for (int j = 0; j < 8; ++j) {
            int kk = kbase + j;
            int t = kk / Cin;
            int c = kk - t * Cin;
            float scale = stats[b * 128 + c].y;
            dst[j] = f2bf(W[((size_t)o * Cin + c) * 7 + t] * scale);
        }
    } else {
        // fold: b2'[b][o] = b2[o] - sum_{c,t} W2[o][c][t]*rstd[b][c]*mu[b][c]
        int b = threadIdx.x >> 7, o = threadIdx.x & 127;
        float sum = 0.f;
        for (int c = 0; c < 128; ++c) {
            float2 st = stats[b * 128 + c];
            float sm = st.x * st.y;
            float ws = 0.f;
#pragma unroll
            for (int t = 0; t < 7; ++t) ws += W[((size_t)o * 128 + c) * 7 + t];
            sum += ws * sm;
        }
        b2out[b * 128 + o] = b2[o] - sum;
    }
}

// ---------------- fused transpose v4 + static-W prepack ----------------
// y in [0,6): transpose fp32 [B][C][N] -> bf16 [B][N][256]. Block = 64c x 256n,
// processed as 4 sub-tiles of 64x64 with double-buffered LDS [2][64][65] fp32.
// Loads for sub-tile st+1 issued before write/read phases of st (latency overlap).
// y == 6: prepack both static W (z==0 only), units of 256 threads, grid-strided.
__global__ void transpose_cast2(const float* __restrict__ up, const float* __restrict__ down,
                                unsigned short* __restrict__ upT, unsigned short* __restrict__ catT,
                                const float* __restrict__ W_up, const float* __restrict__ W_1,
                                unsigned short* __restrict__ Wp0, unsigned short* __restrict__ Wp1,
                                int S1, int N) {
    int y = blockIdx.y;
    if (y == 6) {
        if (blockIdx.z != 0) return;
        int units = 2 * S1 * 2;   // 2*S1*512 threads / 256
        for (int u = blockIdx.x; u < units; u += gridDim.x) {
            int tid = u * 256 + threadIdx.x;
            const float* W = (tid < S1 * 512) ? W_up : W_1;
            unsigned short* Wp = (tid < S1 * 512) ? Wp0 : Wp1;
            int rem = (tid < S1 * 512) ? tid : tid - S1 * 512;
            const int Cin = 256;
            int lane = rem & 63;
            int f = (rem >> 6) & 7;
            int s = rem >> 9;
            int o = f * 16 + (lane & 15);
            int kbase = s * 32 + 8 * (lane >> 4);
            unsigned short* dst = Wp + (size_t)rem * 8;
#pragma unroll
            for (int j = 0; j < 8; ++j) {
                int kk = kbase + j;
                int t = kk / Cin;
                int c = kk - t * Cin;
                dst[j] = f2bf(W[((size_t)o * Cin + c) * 7 + t]);
            }
        }
        return;
    }

    __shared__ float buf[2][64][65];
    int b = blockIdx.z;
    const float* in;  unsigned short* outp;  int c0, coff, C;
    if (y < 4) { in = up;   outp = upT;  c0 = y * 64;       coff = 0;   C = 256; }
    else       { in = down; outp = catT; c0 = (y - 4) * 64; coff = 128; C = 128; }
    int n_base = blockIdx.x * 256;
    const float* inb = in + (size_t)b * C * N;
    unsigned short* outb = outp + (size_t)b * N * 256;
    int tid = threadIdx.x;

    int nq = tid & 15, c_l = tid >> 4;   // load mapping (per 64-n sub-tile)
    int c8 = tid & 7, n_l0 = tid >> 3;   // store mapping

    float4 v[4];
    auto load_regs = [&](int st, float4 vv[4]) {
        int n0s = n_base + st * 64;
        bool nv = (n0s + nq * 4) < N;   // N%4==0 -> all-or-nothing per quad
#pragma unroll
        for (int ci = 0; ci < 4; ++ci) {
            vv[ci] = make_float4(0.f, 0.f, 0.f, 0.f);
            if (nv) vv[ci] = *reinterpret_cast<const float4*>(
                                 inb + (size_t)(c0 + ci * 16 + c_l) * N + n0s + nq * 4);
        }
    };

    load_regs(0, v);
#pragma unroll
    for (int st = 0; st < 4; ++st) {
        float4 vn[4];
        if (st < 3) load_regs(st + 1, vn);     // issue next sub-tile's loads early
        float (*T)[65] = buf[st & 1];
#pragma unroll
        for (int ci = 0; ci < 4; ++ci) {
            int cl = ci * 16 + c_l;
            T[cl][nq * 4 + 0] = v[ci].x;
            T[cl][nq * 4 + 1] = v[ci].y;
            T[cl][nq * 4 + 2] = v[ci].z;
            T[cl][nq * 4 + 3] = v[ci].w;
        }
        __syncthreads();
        int n0s = n_base + st * 64;
#pragma unroll
        for (int p = 0; p < 2; ++p) {
            int n_l = p * 32 + n_l0;
            int n = n0s + n_l;
            if (n < N) {
                short8 u;
#pragma unroll
                for (int j = 0; j < 8; ++j) u[j] = (short)f2bf(T[c8 * 8 + j][n_l]);
                *reinterpret_cast<short8*>(&outb[(size_t)n * 256 + coff + c0 + c8 * 8]) = u;
            }
        }
#pragma unroll
        for (int ci = 0; ci < 4; ++ci) v[ci] = vn[ci];
    }
}

// ---------------- GEMM-ified gather-conv: 256 pts x 128 couts, 8 waves (round-9 proven) ----------------
template<int CS, int LD, bool STATS>
__global__ __launch_bounds__(512, 2) void conv_gemm(
    const unsigned short* __restrict__ src,
    const int* __restrict__ nbrs,
    const unsigned short* __restrict__ Wp, size_t w_bstride_bytes,
    const float* __restrict__ bias, int bias_bstride,
    unsigned short* __restrict__ dst,
    float2* __restrict__ part,
    int N, int coff)
{
    constexpr int ROWB = CS * 2;
    constexpr int SPT  = CS / 32;   // k-steps per tap
    constexpr int S    = SPT * 7;   // total k-steps
    constexpr int BUFB = 24576;     // 16KB A + 8KB W per buffer

    const int tid  = threadIdx.x;
    const int lane = tid & 63;
    const int wid  = tid >> 6;      // 0..7
    const int pg   = wid & 3;       // point quarter (compute)
    const int h    = wid >> 2;      // cout half (compute)
    const int l15  = lane & 15;
    const int ks   = lane >> 4;
    const int b    = blockIdx.y;
    const int pblk = blockIdx.x * 256;

    const char* srcb = (const char*)src + (size_t)b * N * ROWB;
    const char* wbc  = (const char*)Wp + (size_t)b * w_bstride_bytes;

    __shared__ char smem[4 * BUFB];   // 96KB

    int roffA[14];
    {
        int p = pblk + wid * 32 + (lane & 31);
        int pe = p < N ? p : N - 1;
        int offs[7];
        offs[0] = pe * ROWB;
        const int* nb = nbrs + ((size_t)b * N + pe) * 6;
#pragma unroll
        for (int t = 1; t < 7; ++t) offs[t] = nb[t - 1] * ROWB;
#pragma unroll
        for (int t = 0; t < 7; ++t)
#pragma unroll
            for (int i = 0; i < 2; ++i)
                roffA[t * 2 + i] = __shfl(offs[t], i * 16 + (lane >> 2));
    }
    asm volatile("s_waitcnt vmcnt(0)" ::: "memory");
    __builtin_amdgcn_sched_barrier(0);

    const int asw = (((lane & 3) ^ ((lane >> 2) & 3) ^ ((lane >> 4) & 3)) << 4);

    auto stage_all = [&](int t, int kk, int s, int buf) {
        char* base = smem + buf * BUFB;
#pragma unroll
        for (int i = 0; i < 2; ++i)
            glds16(srcb + roffA[t * 2 + i] + kk * 64 + asw,
                   base + (wid * 2 + i) * 1024);
        glds16(wbc + (size_t)s * 8192 + wid * 1024 + lane * 16,
               base + 16384 + wid * 1024);
    };

    f32x4 acc[4][4];
#pragma unroll
    for (int rg = 0; rg < 4; ++rg)
#pragma unroll
        for (int fi = 0; fi < 4; ++fi) acc[rg][fi] = (f32x4){0.f, 0.f, 0.f, 0.f};

    stage_all(0, 0, 0, 0);
    stage_all(1 / SPT, 1 % SPT, 1, 1);
    stage_all(2 / SPT, 2 % SPT, 2, 2);

    const int arsw = (((l15 & 3) ^ ((l15 >> 2) & 3)) << 4);

#pragma unroll
    for (int t = 0; t < 7; ++t) {
#pragma unroll
        for (int kk = 0; kk < SPT; ++kk) {
            const int s = t * SPT + kk;
            if (s + 2 < S)      { asm volatile("s_waitcnt vmcnt(6)" ::: "memory"); }
            else if (s + 1 < S) { asm volatile("s_waitcnt vmcnt(3)" ::: "memory"); }
            else                { asm volatile("s_waitcnt vmcnt(0)" ::: "memory"); }
            __builtin_amdgcn_sched_barrier(0);
            __builtin_amdgcn_s_barrier();
            __builtin_amdgcn_sched_barrier(0);
            if (s + 3 < S) {
                const int s3 = s + 3;
                stage_all(s3 / SPT, s3 % SPT, s3, s3 & 3);
            }

            const char* Ab = smem + (s & 3) * BUFB;
            const char* Wb = Ab + 16384;
            short8 a[4], w[4];
#pragma unroll
            for (int rg = 0; rg < 4; ++rg)
                a[rg] = *(const short8*)(Ab + (pg * 64 + rg * 16 + l15) * 64 +
                                         ((ks << 4) ^ arsw));
#pragma unroll
            for (int fi = 0; fi < 4; ++fi)
                w[fi] = *(const short8*)(Wb + (h * 4 + fi) * 1024 + lane * 16);
            __builtin_amdgcn_s_setprio(1);
#pragma unroll
            for (int rg = 0; rg < 4; ++rg)
#pragma unroll
                for (int fi = 0; fi < 4; ++fi)
                    acc[rg][fi] = __builtin_amdgcn_mfma_f32_16x16x32_bf16(
                        a[rg], w[fi], acc[rg][fi], 0, 0, 0);
            __builtin_amdgcn_s_setprio(0);
        }
    }

    const float* biasb = bias + (size_t)b * bias_bstride + h * 64;
    float bias_v[4];
#pragma unroll
    for (int fi = 0; fi < 4; ++fi) bias_v[fi] = biasb[fi * 16 + l15];

    unsigned short* dstb = dst + (size_t)b * N * LD + coff + h * 64;
#pragma unroll
    for (int rg = 0; rg < 4; ++rg) {
#pragma unroll
        for (int r = 0; r < 4; ++r) {
            int p = pblk + pg * 64 + rg * 16 + ks * 4 + r;
            if (p < N) {
#pragma unroll
                for (int fi = 0; fi < 4; ++fi)
                    dstb[(size_t)p * LD + fi * 16 + l15] = f2bf(acc[rg][fi][r] + bias_v[fi]);
            }
        }
    }

    if constexpr (STATS) {
        float s4[4], q4[4];
#pragma unroll
        for (int fi = 0; fi < 4; ++fi) { s4[fi] = 0.f; q4[fi] = 0.f; }
#pragma unroll
        for (int rg = 0; rg < 4; ++rg) {
#pragma unroll
            for (int r = 0; r < 4; ++r) {
                int p = pblk + pg * 64 + rg * 16 + ks * 4 + r;
                if (p < N) {
#pragma unroll
                    for (int fi = 0; fi < 4; ++fi) {
                        float v = acc[rg][fi][r] + bias_v[fi];
                        s4[fi] += v; q4[fi] += v * v;
                    }
                }
            }
        }
#pragma unroll
        for (int fi = 0; fi < 4; ++fi) {
            s4[fi] += __shfl_xor(s4[fi], 16); s4[fi] += __shfl_xor(s4[fi], 32);
            q4[fi] += __shfl_xor(q4[fi], 16); q4[fi] += __shfl_xor(q4[fi], 32);
        }
        __syncthreads();
        float* shs = (float*)smem;       // [8][64]
        float* shq = shs + 512;
        if (lane < 16) {
#pragma unroll
            for (int fi = 0; fi < 4; ++fi) {
                shs[wid * 64 + fi * 16 + l15] = s4[fi];
                shq[wid * 64 + fi * 16 + l15] = q4[fi];
            }
        }
        __syncthreads();
        if (tid < 128) {
            int c = tid;
            int hh = c >> 6, cl = c & 63;
            float ss = 0.f, qq = 0.f;
#pragma unroll
            for (int p4 = 0; p4 < 4; ++p4) {
                ss += shs[(hh * 4 + p4) * 64 + cl];
                qq += shq[(hh * 4 + p4) * 64 + cl];
            }
            part[((size_t)b * gridDim.x + blockIdx.x) * 128 + c] = make_float2(ss, qq);
        }
    }
}

// ---------------- final reduce of per-block partials -> (mu, rstd) ----------------
__global__ void stats_final(const float2* __restrict__ part, float2* __restrict__ stats,
                            int N, int NB) {
    int b = blockIdx.x;
    int c = threadIdx.x & 127;
    int r = threadIdx.x >> 7;  // 0..7
    float s = 0.f, sq = 0.f;
    const float2* p = part + (size_t)b * NB * 128 + c;
#pragma unroll 4
    for (int i = r; i < NB; i += 8) {
        float2 v = p[(size_t)i * 128];
        s += v.x; sq += v.y;
    }
    __shared__ float shs[8][128], shq[8][128];
    shs[r][c] = s; shq[r][c] = sq;
    __syncthreads();
    if (r == 0) {
#pragma unroll
        for (int i = 1; i < 8; ++i) { s += shs[i][c]; sq += shq[i][c]; }
        float mu = s / N;
        float var = sq / N - mu * mu;
        stats[b * 128 + c] = make_float2(mu, rsqrtf(var + 1e-5f));
    }
}

// ---------------- final v2: out[b][o][n] = (z-mu2)*rstd2 + (x1-mu1)*rstd1 ----------------
__global__ void final_k(const unsigned short* __restrict__ z, const unsigned short* __restrict__ x1,
                        const float2* __restrict__ stats1, const float2* __restrict__ stats2,
                        float* __restrict__ out, int N) {
    __shared__ float tile[32][133];
    int b = blockIdx.z;
    int n0 = blockIdx.x * 128, o0 = blockIdx.y * 32;
    int tid = threadIdx.x;  // 256
    const unsigned short* zb = z  + (size_t)b * N * 128;
    const unsigned short* xb = x1 + (size_t)b * N * 128;

    int oq = tid & 3, n_l0 = tid >> 2;
    float m1[8], r1[8], m2[8], r2[8];
#pragma unroll
    for (int j = 0; j < 8; ++j) {
        float2 s1 = stats1[b * 128 + o0 + oq * 8 + j];
        float2 s2 = stats2[b * 128 + o0 + oq * 8 + j];
        m1[j] = s1.x; r1[j] = s1.y; m2[j] = s2.x; r2[j] = s2.y;
    }
#pragma unroll
    for (int p = 0; p < 2; ++p) {
        int n_l = p * 64 + n_l0;
        int n = n0 + n_l;
        if (n < N) {
            short8 zv = *reinterpret_cast<const short8*>(zb + (size_t)n * 128 + o0 + oq * 8);
            short8 xv = *reinterpret_cast<const short8*>(xb + (size_t)n * 128 + o0 + oq * 8);
#pragma unroll
            for (int j = 0; j < 8; ++j) {
                float v = (bf2f((unsigned short)zv[j]) - m2[j]) * r2[j] +
                          (bf2f((unsigned short)xv[j]) - m1[j]) * r1[j];
                tile[oq * 8 + j][n_l] = v;
            }
        }
    }
    __syncthreads();
    float* ob = out + (size_t)b * 128 * N;
    int nq = tid & 31, o_l = tid >> 5;
    int n = n0 + nq * 4;
    if (n < N) {
#pragma unroll
        for (int pi = 0; pi < 4; ++pi) {
            int orow = pi * 8 + o_l;
            float4 v;
            v.x = tile[orow][nq * 4 + 0];
            v.y = tile[orow][nq * 4 + 1];
            v.z = tile[orow][nq * 4 + 2];
            v.w = tile[orow][nq * 4 + 3];
            *reinterpret_cast<float4*>(&ob[(size_t)(o0 + orow) * N + n]) = v;
        }
    }
}

extern "C" void kernel_launch(void* const* d_in, const int* in_sizes, int n_in,
                              void* d_out, int out_size, void* d_ws, size_t ws_size,
                              hipStream_t stream) {
    const float* from_up   = (const float*)d_in[0];  // [2,256,30000]
    const float* from_down = (const float*)d_in[1];  // [2,128,30000]
    const int*   neighbors = (const int*)d_in[2];    // [2,30000,6]
    const float* W_up = (const float*)d_in[3];
    const float* b_up = (const float*)d_in[4];
    const float* W_1  = (const float*)d_in[5];
    const float* b_1  = (const float*)d_in[6];
    const float* W_2  = (const float*)d_in[7];
    const float* b_2  = (const float*)d_in[8];
    float* out = (float*)d_out;

    const int B = 2, N = 30000;
    const int S1 = 56, S3 = 28;        // K-steps: 1792/32, 896/32
    const int NBLK = (N + 255) / 256;  // 118 conv blocks per batch

    char* ws = (char*)d_ws;
    size_t off = 0;
    auto alloc = [&](size_t bytes) {
        char* p = ws + off;
        off += (bytes + 255) & ~(size_t)255;
        return p;
    };
    unsigned short* upT   = (unsigned short*)alloc((size_t)B * N * 256 * 2);
    unsigned short* catT  = (unsigned short*)alloc((size_t)B * N * 256 * 2);
    unsigned short* x1    = (unsigned short*)alloc((size_t)B * N * 128 * 2);
    unsigned short* Wp0   = (unsigned short*)alloc((size_t)S1 * 512 * 8 * 2);
    unsigned short* Wp1   = (unsigned short*)alloc((size_t)S1 * 512 * 8 * 2);
    unsigned short* Wp2b  = (unsigned short*)alloc((size_t)B * S3 * 512 * 8 * 2);
    float*  b2fold = (float*)alloc((size_t)B * 128 * 4);
    float2* part   = (float2*)alloc((size_t)B * NBLK * 128 * 8);
    float2* stats1 = (float2*)alloc((size_t)B * 128 * 8);
    float2* stats2 = (float2*)alloc((size_t)B * 128 * 8);
    unsigned short* zbuf = upT;  // reuse (upT dead after conv1)

    // transpose both inputs + prepack both static weights (one launch)
    transpose_cast2<<<dim3((N + 255) / 256, 7, B), 256, 0, stream>>>(
        from_up, from_down, upT, catT, W_up, W_1, Wp0, Wp1, S1, N);

    dim3 cgrid(NBLK, B);
    // conv1: upT (Cin=256) -> catT[:, 0:128]
    conv_gemm<256, 256, false><<<cgrid, 512, 0, stream>>>(
        upT, neighbors, Wp0, 0, b_up, 0, catT, nullptr, N, 0);
    // conv2: catT (Cin=256) -> x1, fused stats partials
    conv_gemm<256, 128, true><<<cgrid, 512, 0, stream>>>(
        catT, neighbors, Wp1, 0, b_1, 0, x1, part, N, 0);
    stats_final<<<B, 1024, 0, stream>>>((const float2*)part, stats1, N, NBLK);

    // fold norm1 into conv3's weights/bias (per batch), one launch
    int nPre = (B * S3 * 512) / 256;  // 112
    prepack_scaled_fold<<<nPre + 1, 256, 0, stream>>>(W_2, stats1, Wp2b, b_2, b2fold, S3, nPre);

    // conv3: x1 (Cin=128, scaled weights) -> zbuf, fused stats partials
    conv_gemm<128, 128, true><<<cgrid, 512, 0, stream>>>(
        x1, neighbors, Wp2b, (size_t)S3 * 8192, b2fold, 128, zbuf, part, N, 0);
    stats_final<<<B, 1024, 0, stream>>>((const float2*)part, stats2, N, NBLK);

    // final: normalize z, add recomputed x1n, transpose to [B][128][N] fp32
    final_k<<<dim3((N + 127) / 128, 4, B), 256, 0, stream>>>(zbuf, x1, stats1, stats2, out, N);
}